// Round 1
// baseline (703.023 us; speedup 1.0000x reference)
//
#include <hip/hip_runtime.h>
#include <hip/hip_bf16.h>

constexpr int kD  = 1024;
constexpr int kH  = 16;
constexpr int kHD = 64;
constexpr int kS  = 64;
constexpr int kE  = 16;
constexpr int kB  = 32;
constexpr int kSB = kS * kB;   // 2048 (s,b) pairs

struct __align__(8) bf4 { __hip_bfloat16 v[4]; };

__device__ __forceinline__ float4 ld4(const float* p) { return *(const float4*)p; }
__device__ __forceinline__ float4 ld4(const __hip_bfloat16* p) {
  bf4 u = *(const bf4*)p;
  return make_float4(__bfloat162float(u.v[0]), __bfloat162float(u.v[1]),
                     __bfloat162float(u.v[2]), __bfloat162float(u.v[3]));
}

// out[j] = (dot(Wmat[j,:], vec) + bias[j]) * scale   -- one block per row j
__global__ __launch_bounds__(256) void k_rowdot(const float* __restrict__ Wmat,
                                                const float* __restrict__ vec,
                                                const float* __restrict__ bias,
                                                float scale, float* __restrict__ outv) {
  int j = blockIdx.x;
  int t = threadIdx.x;
  const float4* w4 = (const float4*)(Wmat + (size_t)j * kD);
  const float4* v4 = (const float4*)vec;
  float4 a = w4[t], b = v4[t];
  float acc = a.x * b.x + a.y * b.y + a.z * b.z + a.w * b.w;
  #pragma unroll
  for (int o = 32; o >= 1; o >>= 1) acc += __shfl_xor(acc, o);
  __shared__ float red[4];
  if ((t & 63) == 0) red[t >> 6] = acc;
  __syncthreads();
  if (t == 0) outv[j] = (red[0] + red[1] + red[2] + red[3] + bias[j]) * scale;
}

// wmat[h,d] = sum_j qs[h*64+j] * Wk_in[h*64+j, d]
__global__ __launch_bounds__(256) void k_w(const float* __restrict__ qs,
                                           const float* __restrict__ Wk_in,
                                           float* __restrict__ wmat) {
  int tid = blockIdx.x * 256 + threadIdx.x;
  int h = tid >> 10, d = tid & (kD - 1);
  float acc = 0.f;
  #pragma unroll 8
  for (int j = 0; j < kHD; j++)
    acc = fmaf(qs[h * kHD + j], Wk_in[(size_t)(h * kHD + j) * kD + d], acc);
  wmat[(size_t)h * kD + d] = acc;
}

// umat[h,t] = sum_d wmat[h,d] * Wk_lin[d, t]
__global__ __launch_bounds__(256) void k_u(const float* __restrict__ wmat,
                                           const float* __restrict__ Wk_lin,
                                           float* __restrict__ umat) {
  int tid = blockIdx.x * 256 + threadIdx.x;
  int h = tid >> 10, tcol = tid & (kD - 1);
  float acc = 0.f;
  #pragma unroll 4
  for (int d = 0; d < kD; d++)
    acc = fmaf(wmat[h * kD + d], Wk_lin[(size_t)d * kD + tcol], acc);
  umat[(size_t)h * kD + tcol] = acc;
}

// cvec[h] = dot(wmat[h,:], bk_lin) + dot(qs[hslice], bk_in[hslice])
__global__ __launch_bounds__(256) void k_c(const float* __restrict__ wmat,
                                           const float* __restrict__ bk_lin,
                                           const float* __restrict__ qs,
                                           const float* __restrict__ bk_in,
                                           float* __restrict__ cvec) {
  int t = threadIdx.x;
  int h = t >> 4, l = t & 15;
  float acc = 0.f;
  for (int d = l; d < kD; d += 16) acc += wmat[h * kD + d] * bk_lin[d];
  for (int j = l; j < kHD; j += 16) acc += qs[h * kHD + j] * bk_in[h * kHD + j];
  #pragma unroll
  for (int o = 8; o >= 1; o >>= 1) acc += __shfl_xor(acc, o, 16);
  if (l == 0) cvec[h] = acc;
}

// out[c*1024+k] = in[k*1024+c]
__global__ void k_transpose(const float* __restrict__ in, float* __restrict__ out) {
  __shared__ float tile[32][33];
  int x = blockIdx.x * 32 + threadIdx.x;
  int y0 = blockIdx.y * 32;
  for (int i = threadIdx.y; i < 32; i += 8)
    tile[i][threadIdx.x] = in[(size_t)(y0 + i) * kD + x];
  __syncthreads();
  int xo = blockIdx.y * 32 + threadIdx.x;
  int yo0 = blockIdx.x * 32;
  for (int i = threadIdx.y; i < 32; i += 8)
    out[(size_t)(yo0 + i) * kD + xo] = tile[threadIdx.x][i];
}

// Fused: scores -> softmax over E -> eagg[sb,h,:] (bf16)
__global__ __launch_bounds__(256) void k_attn_eagg(const float* __restrict__ ent,
                                                   const unsigned char* __restrict__ pmask,
                                                   const float* __restrict__ umat,
                                                   const float* __restrict__ cvec,
                                                   __hip_bfloat16* __restrict__ eagg) {
  __shared__ __hip_bfloat16 ent_s[kE][kD + 8];
  __shared__ float attn_s[kH][kE + 1];
  int sb = blockIdx.x;
  int s = sb >> 5, b = sb & 31;
  int t = threadIdx.x;
  // stage E x D entity tile -> LDS (bf16)
  const float* src = ent + (size_t)(s * kE) * kB * kD + (size_t)b * kD;
  for (int i = t; i < kE * kD / 4; i += 256) {
    int e = i >> 8, f = i & 255;
    float4 v = *(const float4*)(src + (size_t)e * kB * kD + f * 4);
    bf4 pk;
    pk.v[0] = __float2bfloat16(v.x); pk.v[1] = __float2bfloat16(v.y);
    pk.v[2] = __float2bfloat16(v.z); pk.v[3] = __float2bfloat16(v.w);
    *(bf4*)&ent_s[e][f * 4] = pk;
  }
  __syncthreads();
  // scores: thread (h = t>>4, e = t&15)
  int h = t >> 4, e = t & 15;
  const float* urow = umat + (size_t)h * kD;
  float acc = 0.f;
  #pragma unroll 4
  for (int d = 0; d < kD; d += 4) {
    bf4 ev = *(const bf4*)&ent_s[e][d];
    float4 uv = *(const float4*)&urow[d];
    acc += __bfloat162float(ev.v[0]) * uv.x + __bfloat162float(ev.v[1]) * uv.y +
           __bfloat162float(ev.v[2]) * uv.z + __bfloat162float(ev.v[3]) * uv.w;
  }
  float sc = acc + cvec[h];
  if (pmask[(size_t)(s * kE + e) * kB + b]) sc = -INFINITY;
  // softmax over e within 16-lane groups
  float m = sc;
  #pragma unroll
  for (int o = 8; o >= 1; o >>= 1) m = fmaxf(m, __shfl_xor(m, o, 16));
  float ex = __expf(sc - m);
  float sum = ex;
  #pragma unroll
  for (int o = 8; o >= 1; o >>= 1) sum += __shfl_xor(sum, o, 16);
  attn_s[h][e] = ex / sum;
  __syncthreads();
  // eagg[sb,h,d] = sum_e attn[h,e] * ent[e,d]
  int h2 = t >> 4, lane = t & 15;
  float aw[kE];
  #pragma unroll
  for (int e2 = 0; e2 < kE; e2++) aw[e2] = attn_s[h2][e2];
  __hip_bfloat16* dst = eagg + ((size_t)sb * kH + h2) * kD;
  for (int j = 0; j < kD / 64; j++) {
    int d0 = j * 64 + lane * 4;
    float a0 = 0.f, a1 = 0.f, a2 = 0.f, a3 = 0.f;
    #pragma unroll
    for (int e2 = 0; e2 < kE; e2++) {
      bf4 ev = *(const bf4*)&ent_s[e2][d0];
      float w = aw[e2];
      a0 = fmaf(w, __bfloat162float(ev.v[0]), a0);
      a1 = fmaf(w, __bfloat162float(ev.v[1]), a1);
      a2 = fmaf(w, __bfloat162float(ev.v[2]), a2);
      a3 = fmaf(w, __bfloat162float(ev.v[3]), a3);
    }
    bf4 o;
    o.v[0] = __float2bfloat16(a0); o.v[1] = __float2bfloat16(a1);
    o.v[2] = __float2bfloat16(a2); o.v[3] = __float2bfloat16(a3);
    *(bf4*)(dst + d0) = o;
  }
}

// C[m,n] = sum_k A[m,k]*B[n,k] + bias[n]; 64x64 tile, BK=32, batched over z
template <typename TA>
__global__ __launch_bounds__(256) void k_gemm_nt(
    const TA* __restrict__ Abase, int lda, long aBatch,
    const float* __restrict__ Bbase, int ldb, long bBatch,
    float* __restrict__ Cbase, int ldc, long cBatch,
    const float* __restrict__ bias, long biasBatch, int Ksz) {
  const TA* Ag = Abase + (size_t)blockIdx.z * aBatch;
  const float* Bg = Bbase + (size_t)blockIdx.z * bBatch;
  float* Cg = Cbase + (size_t)blockIdx.z * cBatch;
  const int m0 = blockIdx.x * 64, n0 = blockIdx.y * 64;
  __shared__ float As[32][68];
  __shared__ float Bs[32][68];
  const int t = threadIdx.x;
  const int tx = t & 15, ty = t >> 4;
  float acc[4][4] = {};
  for (int k0 = 0; k0 < Ksz; k0 += 32) {
    #pragma unroll
    for (int i = t; i < 512; i += 256) {
      int row = i >> 3, kq = i & 7;
      float4 v = ld4(Ag + (size_t)(m0 + row) * lda + k0 + kq * 4);
      As[kq * 4 + 0][row] = v.x; As[kq * 4 + 1][row] = v.y;
      As[kq * 4 + 2][row] = v.z; As[kq * 4 + 3][row] = v.w;
    }
    #pragma unroll
    for (int i = t; i < 512; i += 256) {
      int row = i >> 3, kq = i & 7;
      float4 v = ld4(Bg + (size_t)(n0 + row) * ldb + k0 + kq * 4);
      Bs[kq * 4 + 0][row] = v.x; Bs[kq * 4 + 1][row] = v.y;
      Bs[kq * 4 + 2][row] = v.z; Bs[kq * 4 + 3][row] = v.w;
    }
    __syncthreads();
    #pragma unroll
    for (int kk = 0; kk < 32; kk++) {
      float4 a4 = *(const float4*)&As[kk][ty * 4];
      float4 b4 = *(const float4*)&Bs[kk][tx * 4];
      float av[4] = {a4.x, a4.y, a4.z, a4.w};
      float bv[4] = {b4.x, b4.y, b4.z, b4.w};
      #pragma unroll
      for (int i = 0; i < 4; i++)
        #pragma unroll
        for (int j = 0; j < 4; j++)
          acc[i][j] = fmaf(av[i], bv[j], acc[i][j]);
    }
    __syncthreads();
  }
  float bv[4] = {0.f, 0.f, 0.f, 0.f};
  if (bias) {
    const float* bp = bias + (size_t)blockIdx.z * biasBatch + n0 + tx * 4;
    bv[0] = bp[0]; bv[1] = bp[1]; bv[2] = bp[2]; bv[3] = bp[3];
  }
  #pragma unroll
  for (int i = 0; i < 4; i++) {
    float4 o = make_float4(acc[i][0] + bv[0], acc[i][1] + bv[1],
                           acc[i][2] + bv[2], acc[i][3] + bv[3]);
    *(float4*)&Cg[(size_t)(m0 + ty * 4 + i) * ldc + n0 + tx * 4] = o;
  }
}

extern "C" void kernel_launch(void* const* d_in, const int* in_sizes, int n_in,
                              void* d_out, int out_size, void* d_ws, size_t ws_size,
                              hipStream_t stream) {
  const float* ent            = (const float*)d_in[0];
  const unsigned char* pmask  = (const unsigned char*)d_in[1];
  const float* query          = (const float*)d_in[3];
  const float* Wk_lin         = (const float*)d_in[4];
  const float* bk_lin         = (const float*)d_in[5];
  const float* Wv_lin         = (const float*)d_in[6];
  const float* bv_lin         = (const float*)d_in[7];
  const float* Wq_in          = (const float*)d_in[8];
  const float* bq_in          = (const float*)d_in[9];
  const float* Wk_in          = (const float*)d_in[10];
  const float* bk_in          = (const float*)d_in[11];
  const float* Wv_in          = (const float*)d_in[12];
  const float* bv_in          = (const float*)d_in[13];
  const float* Wo             = (const float*)d_in[14];
  const float* bo             = (const float*)d_in[15];
  float* out = (float*)d_out;

  float* p = (float*)d_ws;
  float* qs   = p; p += 1024;        // scaled projected query
  float* wmat = p; p += kH * kD;     // w[h,d]
  float* umat = p; p += kH * kD;     // u[h,t]
  float* cvec = p; p += 256;         // c[h] (16 used)
  float* cb   = p; p += kD;          // Wv_in@bv_lin + bv_in
  float* WvlT = p; p += kD * kD;     // Wv_lin^T
  float* Mmat = p; p += kD * kD;     // Wv_in @ Wv_lin
  float* ctx  = p; p += kSB * kD;    // [SB, D]
  __hip_bfloat16* eagg = (__hip_bfloat16*)p;  // [SB, H, D] bf16

  // ---- tiny precomputes (all folded weights) ----
  k_rowdot<<<kD, 256, 0, stream>>>(Wq_in, query, bq_in, 0.125f, qs);
  k_w<<<64, 256, 0, stream>>>(qs, Wk_in, wmat);
  k_u<<<64, 256, 0, stream>>>(wmat, Wk_lin, umat);
  k_c<<<1, 256, 0, stream>>>(wmat, bk_lin, qs, bk_in, cvec);
  k_rowdot<<<kD, 256, 0, stream>>>(Wv_in, bv_lin, bv_in, 1.0f, cb);
  k_transpose<<<dim3(32, 32), dim3(32, 8), 0, stream>>>(Wv_lin, WvlT);
  // M = Wv_in @ Wv_lin  (NT with pre-transposed Wv_lin)
  k_gemm_nt<<<dim3(16, 16, 1), 256, 0, stream>>>(
      Wv_in, kD, 0L, WvlT, kD, 0L, Mmat, kD, 0L, (const float*)nullptr, 0L, kD);

  // ---- main pipeline ----
  k_attn_eagg<<<kSB, 256, 0, stream>>>(ent, pmask, umat, cvec, eagg);
  // ctx[sb, h*64+j] = M_h @ eagg[sb,h,:] + cb   (batched over h = z)
  k_gemm_nt<<<dim3(kSB / 64, 1, kH), 256, 0, stream>>>(
      eagg, kH * kD, (long)kD, Mmat, kD, (long)(kHD * kD),
      ctx, kD, (long)kHD, cb, (long)kHD, kD);
  // out = ctx @ Wo^T + bo
  k_gemm_nt<<<dim3(kSB / 64, kD / 64, 1), 256, 0, stream>>>(
      ctx, kD, 0L, Wo, kD, 0L, out, kD, 0L, bo, 0L, kD);
}

// Round 2
// 536.503 us; speedup vs baseline: 1.3104x; 1.3104x over previous
//
#include <hip/hip_runtime.h>
#include <hip/hip_bf16.h>

constexpr int kD  = 1024;
constexpr int kH  = 16;
constexpr int kHD = 64;
constexpr int kS  = 64;
constexpr int kE  = 16;
constexpr int kB  = 32;
constexpr int kSB = kS * kB;   // 2048 (s,b) pairs

typedef __attribute__((ext_vector_type(8))) short bfvec8;   // 8 bf16 in 4 VGPRs
typedef __attribute__((ext_vector_type(4))) float fvec4;    // MFMA acc

struct __align__(8)  bf4  { __hip_bfloat16 v[4]; };
struct __align__(16) bf8v { __hip_bfloat16 v[8]; };

// ---------------- tiny precompute kernels ----------------

// out[j] = (dot(Wmat[j,:], vec) + bias[j]) * scale   -- one block per row j
__global__ __launch_bounds__(256) void k_rowdot(const float* __restrict__ Wmat,
                                                const float* __restrict__ vec,
                                                const float* __restrict__ bias,
                                                float scale, float* __restrict__ outv) {
  int j = blockIdx.x;
  int t = threadIdx.x;
  const float4* w4 = (const float4*)(Wmat + (size_t)j * kD);
  const float4* v4 = (const float4*)vec;
  float4 a = w4[t], b = v4[t];
  float acc = a.x * b.x + a.y * b.y + a.z * b.z + a.w * b.w;
  #pragma unroll
  for (int o = 32; o >= 1; o >>= 1) acc += __shfl_xor(acc, o);
  __shared__ float red[4];
  if ((t & 63) == 0) red[t >> 6] = acc;
  __syncthreads();
  if (t == 0) outv[j] = (red[0] + red[1] + red[2] + red[3] + bias[j]) * scale;
}

// wmat[h,d] = sum_j qs[h*64+j] * Wk_in[h*64+j, d]
__global__ __launch_bounds__(256) void k_w(const float* __restrict__ qs,
                                           const float* __restrict__ Wk_in,
                                           float* __restrict__ wmat) {
  int tid = blockIdx.x * 256 + threadIdx.x;
  int h = tid >> 10, d = tid & (kD - 1);
  float acc = 0.f;
  #pragma unroll 8
  for (int j = 0; j < kHD; j++)
    acc = fmaf(qs[h * kHD + j], Wk_in[(size_t)(h * kHD + j) * kD + d], acc);
  wmat[(size_t)h * kD + d] = acc;
}

// umat[h,t] = sum_d wmat[h,d] * Wk_lin[d, t]
__global__ __launch_bounds__(256) void k_u(const float* __restrict__ wmat,
                                           const float* __restrict__ Wk_lin,
                                           float* __restrict__ umat) {
  int tid = blockIdx.x * 256 + threadIdx.x;
  int h = tid >> 10, tcol = tid & (kD - 1);
  float acc = 0.f;
  #pragma unroll 4
  for (int d = 0; d < kD; d++)
    acc = fmaf(wmat[h * kD + d], Wk_lin[(size_t)d * kD + tcol], acc);
  umat[(size_t)h * kD + tcol] = acc;
}

// cvec[h] = dot(wmat[h,:], bk_lin) + dot(qs[hslice], bk_in[hslice])
__global__ __launch_bounds__(256) void k_c(const float* __restrict__ wmat,
                                           const float* __restrict__ bk_lin,
                                           const float* __restrict__ qs,
                                           const float* __restrict__ bk_in,
                                           float* __restrict__ cvec) {
  int t = threadIdx.x;
  int h = t >> 4, l = t & 15;
  float acc = 0.f;
  for (int d = l; d < kD; d += 16) acc += wmat[h * kD + d] * bk_lin[d];
  for (int j = l; j < kHD; j += 16) acc += qs[h * kHD + j] * bk_in[h * kHD + j];
  #pragma unroll
  for (int o = 8; o >= 1; o >>= 1) acc += __shfl_xor(acc, o, 16);
  if (l == 0) cvec[h] = acc;
}

// WvlT_bf[c][k] = bf16(Wv_lin[k][c])  (transpose + convert)
__global__ void k_transpose_cvt(const float* __restrict__ in,
                                __hip_bfloat16* __restrict__ out) {
  __shared__ float tile[32][33];
  int x = blockIdx.x * 32 + threadIdx.x;
  int y0 = blockIdx.y * 32;
  for (int i = threadIdx.y; i < 32; i += 8)
    tile[i][threadIdx.x] = in[(size_t)(y0 + i) * kD + x];
  __syncthreads();
  int xo = blockIdx.y * 32 + threadIdx.x;
  int yo0 = blockIdx.x * 32;
  for (int i = threadIdx.y; i < 32; i += 8)
    out[(size_t)(yo0 + i) * kD + xo] = __float2bfloat16(tile[threadIdx.x][i]);
}

// Wo2[n][k] = Wo2[n][k+1024] = bf16(Wo[n][k])   (K-duplicated for split-ctx GEMM)
__global__ __launch_bounds__(256) void k_cvt_dup(const float* __restrict__ in,
                                                 __hip_bfloat16* __restrict__ out) {
  int tid = blockIdx.x * 256 + threadIdx.x;   // 1M threads
  int n = tid >> 10, k = tid & 1023;
  __hip_bfloat16 v = __float2bfloat16(in[(size_t)n * kD + k]);
  out[(size_t)n * 2048 + k] = v;
  out[(size_t)n * 2048 + 1024 + k] = v;
}

// ---------------- fused attention: scores -> softmax -> eagg (bf16) ----------------

__global__ __launch_bounds__(256) void k_attn_eagg(const float* __restrict__ ent,
                                                   const unsigned char* __restrict__ pmask,
                                                   const float* __restrict__ umat,
                                                   const float* __restrict__ cvec,
                                                   __hip_bfloat16* __restrict__ eagg) {
  __shared__ __hip_bfloat16 ent_s[kE][kD + 8];
  __shared__ float attn_s[kH][kE + 1];
  int sb = blockIdx.x;
  int s = sb >> 5, b = sb & 31;
  int t = threadIdx.x;
  // stage E x D entity tile -> LDS (bf16), 8 floats per iter, 16B LDS writes
  const float* src = ent + (size_t)(s * kE) * kB * kD + (size_t)b * kD;
  for (int i = t; i < kE * kD / 8; i += 256) {
    int e = i >> 7, f = (i & 127) * 8;
    const float4* p = (const float4*)(src + (size_t)e * kB * kD + f);
    float4 v0 = p[0], v1 = p[1];
    bf8v pk;
    pk.v[0] = __float2bfloat16(v0.x); pk.v[1] = __float2bfloat16(v0.y);
    pk.v[2] = __float2bfloat16(v0.z); pk.v[3] = __float2bfloat16(v0.w);
    pk.v[4] = __float2bfloat16(v1.x); pk.v[5] = __float2bfloat16(v1.y);
    pk.v[6] = __float2bfloat16(v1.z); pk.v[7] = __float2bfloat16(v1.w);
    *(bf8v*)&ent_s[e][f] = pk;
  }
  __syncthreads();
  // scores: thread (h = t>>4, e = t&15); b128 LDS reads
  int h = t >> 4, e = t & 15;
  const float4* u4 = (const float4*)(umat + (size_t)h * kD);
  float acc = 0.f;
  #pragma unroll 4
  for (int d = 0; d < kD; d += 8) {
    bf8v ev = *(const bf8v*)&ent_s[e][d];
    float4 u0 = u4[d >> 2], u1 = u4[(d >> 2) + 1];
    acc += __bfloat162float(ev.v[0]) * u0.x + __bfloat162float(ev.v[1]) * u0.y +
           __bfloat162float(ev.v[2]) * u0.z + __bfloat162float(ev.v[3]) * u0.w +
           __bfloat162float(ev.v[4]) * u1.x + __bfloat162float(ev.v[5]) * u1.y +
           __bfloat162float(ev.v[6]) * u1.z + __bfloat162float(ev.v[7]) * u1.w;
  }
  float sc = acc + cvec[h];
  if (pmask[(size_t)(s * kE + e) * kB + b]) sc = -INFINITY;
  // softmax over e within 16-lane groups
  float m = sc;
  #pragma unroll
  for (int o = 8; o >= 1; o >>= 1) m = fmaxf(m, __shfl_xor(m, o, 16));
  float ex = __expf(sc - m);
  float sum = ex;
  #pragma unroll
  for (int o = 8; o >= 1; o >>= 1) sum += __shfl_xor(sum, o, 16);
  attn_s[h][e] = ex / sum;
  __syncthreads();
  // eagg[sb,h,d] = sum_e attn[h,e] * ent[e,d]; 8 d per lane per iter
  int h2 = t >> 4, lane = t & 15;
  float aw[kE];
  #pragma unroll
  for (int e2 = 0; e2 < kE; e2++) aw[e2] = attn_s[h2][e2];
  __hip_bfloat16* dst = eagg + ((size_t)sb * kH + h2) * kD;
  for (int j = 0; j < kD; j += 128) {
    int d0 = j + lane * 8;
    float a[8] = {};
    #pragma unroll
    for (int e2 = 0; e2 < kE; e2++) {
      bf8v ev = *(const bf8v*)&ent_s[e2][d0];
      float w = aw[e2];
      #pragma unroll
      for (int q = 0; q < 8; q++) a[q] = fmaf(w, __bfloat162float(ev.v[q]), a[q]);
    }
    bf8v o;
    #pragma unroll
    for (int q = 0; q < 8; q++) o.v[q] = __float2bfloat16(a[q]);
    *(bf8v*)(dst + d0) = o;
  }
}

// ---------------- bf16 MFMA GEMM (NT): C[m,n] = sum_k A[m,k]*B[n,k] (+bias) ----------------
// 64x64 tile, 4 waves; wave w owns rows [w*16, w*16+16), 4 n-frags of 16.
// MODE 0: f32 out + bias. MODE 1: bf16 hi at col n, bf16 lo at col n+1024 (+bias).
// MODE 2: bf16 out, no bias.

__device__ __forceinline__ void stage_row(const __hip_bfloat16* g, __hip_bfloat16* s) {
  *(bf8v*)s = *(const bf8v*)g;
}
__device__ __forceinline__ void stage_row(const float* g, __hip_bfloat16* s) {
  const float4* p = (const float4*)g;
  float4 v0 = p[0], v1 = p[1];
  bf8v pk;
  pk.v[0] = __float2bfloat16(v0.x); pk.v[1] = __float2bfloat16(v0.y);
  pk.v[2] = __float2bfloat16(v0.z); pk.v[3] = __float2bfloat16(v0.w);
  pk.v[4] = __float2bfloat16(v1.x); pk.v[5] = __float2bfloat16(v1.y);
  pk.v[6] = __float2bfloat16(v1.z); pk.v[7] = __float2bfloat16(v1.w);
  *(bf8v*)s = pk;
}

template <int MODE, typename TA, typename TB, typename TC>
__global__ __launch_bounds__(256) void k_gemm_mfma(
    const TA* __restrict__ Abase, int lda, long aBatch,
    const TB* __restrict__ Bbase, int ldb, long bBatch,
    TC* __restrict__ Cbase, int ldc, long cBatch,
    const float* __restrict__ bias, long biasBatch, int Ksz) {
  const TA* Ag = Abase + (size_t)blockIdx.z * aBatch;
  const TB* Bg = Bbase + (size_t)blockIdx.z * bBatch;
  TC* Cg = Cbase + (size_t)blockIdx.z * cBatch;
  const float* biasp = bias ? bias + (size_t)blockIdx.z * biasBatch : nullptr;
  const int m0 = blockIdx.x * 64, n0 = blockIdx.y * 64;
  __shared__ __hip_bfloat16 As[64][72];
  __shared__ __hip_bfloat16 Bs[64][72];
  const int t = threadIdx.x;
  const int l = t & 63, w = t >> 6;
  const int quad = l >> 4, col = l & 15;
  fvec4 acc[4] = {};
  for (int k0 = 0; k0 < Ksz; k0 += 64) {
    #pragma unroll
    for (int c = t; c < 512; c += 256) {
      int row = c >> 3, kq = (c & 7) * 8;
      stage_row(Ag + (size_t)(m0 + row) * lda + k0 + kq, &As[row][kq]);
      stage_row(Bg + (size_t)(n0 + row) * ldb + k0 + kq, &Bs[row][kq]);
    }
    __syncthreads();
    #pragma unroll
    for (int ks = 0; ks < 64; ks += 32) {
      bfvec8 a = *(const bfvec8*)&As[w * 16 + col][ks + quad * 8];
      #pragma unroll
      for (int nt = 0; nt < 4; nt++) {
        bfvec8 b = *(const bfvec8*)&Bs[nt * 16 + col][ks + quad * 8];
        acc[nt] = __builtin_amdgcn_mfma_f32_16x16x32_bf16(a, b, acc[nt], 0, 0, 0);
      }
    }
    __syncthreads();
  }
  #pragma unroll
  for (int nt = 0; nt < 4; nt++) {
    int n = n0 + nt * 16 + col;
    float bv = biasp ? biasp[n] : 0.f;
    #pragma unroll
    for (int i = 0; i < 4; i++) {
      int r = m0 + w * 16 + quad * 4 + i;
      float v = acc[nt][i] + bv;
      if constexpr (MODE == 0) {
        ((float*)Cg)[(size_t)r * ldc + n] = v;
      } else if constexpr (MODE == 1) {
        __hip_bfloat16 hi = __float2bfloat16(v);
        float lo = v - __bfloat162float(hi);
        ((__hip_bfloat16*)Cg)[(size_t)r * ldc + n] = hi;
        ((__hip_bfloat16*)Cg)[(size_t)r * ldc + n + 1024] = __float2bfloat16(lo);
      } else {
        ((__hip_bfloat16*)Cg)[(size_t)r * ldc + n] = __float2bfloat16(v);
      }
    }
  }
}

extern "C" void kernel_launch(void* const* d_in, const int* in_sizes, int n_in,
                              void* d_out, int out_size, void* d_ws, size_t ws_size,
                              hipStream_t stream) {
  const float* ent            = (const float*)d_in[0];
  const unsigned char* pmask  = (const unsigned char*)d_in[1];
  const float* query          = (const float*)d_in[3];
  const float* Wk_lin         = (const float*)d_in[4];
  const float* bk_lin         = (const float*)d_in[5];
  const float* Wv_lin         = (const float*)d_in[6];
  const float* bv_lin         = (const float*)d_in[7];
  const float* Wq_in          = (const float*)d_in[8];
  const float* bq_in          = (const float*)d_in[9];
  const float* Wk_in          = (const float*)d_in[10];
  const float* bk_in          = (const float*)d_in[11];
  const float* Wv_in          = (const float*)d_in[12];
  const float* bv_in          = (const float*)d_in[13];
  const float* Wo             = (const float*)d_in[14];
  const float* bo             = (const float*)d_in[15];
  float* out = (float*)d_out;

  float* p = (float*)d_ws;
  float* qs   = p; p += 1024;        // scaled projected query
  float* wmat = p; p += kH * kD;     // w[h,d]
  float* umat = p; p += kH * kD;     // u[h,t]
  float* cvec = p; p += 256;         // c[h] (16 used)
  float* cb   = p; p += kD;          // Wv_in@bv_lin + bv_in
  __hip_bfloat16* bp = (__hip_bfloat16*)p;
  __hip_bfloat16* WvlT = bp; bp += (size_t)kD * kD;        // Wv_lin^T bf16
  __hip_bfloat16* Mmat = bp; bp += (size_t)kD * kD;        // Wv_in @ Wv_lin bf16
  __hip_bfloat16* Wo2  = bp; bp += (size_t)kD * 2048;      // Wo bf16, K-duplicated
  __hip_bfloat16* ctx2 = bp; bp += (size_t)kSB * 2048;     // ctx hi|lo bf16
  __hip_bfloat16* eagg = bp;                               // [SB, H, D] bf16

  // ---- tiny precomputes (folded weights) ----
  k_rowdot<<<kD, 256, 0, stream>>>(Wq_in, query, bq_in, 0.125f, qs);
  k_w<<<64, 256, 0, stream>>>(qs, Wk_in, wmat);
  k_u<<<64, 256, 0, stream>>>(wmat, Wk_lin, umat);
  k_c<<<1, 256, 0, stream>>>(wmat, bk_lin, qs, bk_in, cvec);
  k_rowdot<<<kD, 256, 0, stream>>>(Wv_in, bv_lin, bv_in, 1.0f, cb);
  k_transpose_cvt<<<dim3(32, 32), dim3(32, 8), 0, stream>>>(Wv_lin, WvlT);
  k_cvt_dup<<<4096, 256, 0, stream>>>(Wo, Wo2);
  // M = Wv_in @ Wv_lin  (A = f32 Wv_in converted in staging, B = WvlT bf16)
  k_gemm_mfma<2><<<dim3(16, 16, 1), 256, 0, stream>>>(
      Wv_in, kD, 0L, WvlT, kD, 0L, Mmat, kD, 0L, (const float*)nullptr, 0L, kD);

  // ---- main pipeline ----
  k_attn_eagg<<<kSB, 256, 0, stream>>>(ent, pmask, umat, cvec, eagg);
  // ctx[sb, h*64+j] = M_h @ eagg[sb,h,:] + cb  -> split hi/lo into ctx2 (batched over h)
  k_gemm_mfma<1><<<dim3(kSB / 64, 1, kH), 256, 0, stream>>>(
      eagg, kH * kD, (long)kD, Mmat, kD, (long)(kHD * kD),
      ctx2, 2048, (long)kHD, cb, (long)kHD, kD);
  // out = (ctx_hi + ctx_lo) @ Wo_bf^T + bo   (K = 2048 concat)
  k_gemm_mfma<0><<<dim3(kSB / 64, kD / 64, 1), 256, 0, stream>>>(
      ctx2, 2048, 0L, Wo2, 2048, 0L, out, kD, 0L, bo, 0L, 2048);
}

// Round 3
// 375.102 us; speedup vs baseline: 1.8742x; 1.4303x over previous
//
#include <hip/hip_runtime.h>
#include <hip/hip_bf16.h>

constexpr int kD  = 1024;
constexpr int kH  = 16;
constexpr int kHD = 64;
constexpr int kS  = 64;
constexpr int kE  = 16;
constexpr int kB  = 32;
constexpr int kSB = kS * kB;   // 2048 (s,b) pairs

typedef __attribute__((ext_vector_type(8))) short bfvec8;   // 8 bf16 (4 VGPRs)
typedef __attribute__((ext_vector_type(4))) float fvec4;    // MFMA acc

struct __align__(8)  bf4  { __hip_bfloat16 v[4]; };
struct __align__(16) bf8v { __hip_bfloat16 v[8]; };

// ---------------- tiny precompute kernels ----------------

// out[j] = (dot(Wmat[j,:], vec) + bias[j]) * scale   -- one block per row j
__global__ __launch_bounds__(256) void k_rowdot(const float* __restrict__ Wmat,
                                                const float* __restrict__ vec,
                                                const float* __restrict__ bias,
                                                float scale, float* __restrict__ outv) {
  int j = blockIdx.x;
  int t = threadIdx.x;
  const float4* w4 = (const float4*)(Wmat + (size_t)j * kD);
  const float4* v4 = (const float4*)vec;
  float4 a = w4[t], b = v4[t];
  float acc = a.x * b.x + a.y * b.y + a.z * b.z + a.w * b.w;
  #pragma unroll
  for (int o = 32; o >= 1; o >>= 1) acc += __shfl_xor(acc, o);
  __shared__ float red[4];
  if ((t & 63) == 0) red[t >> 6] = acc;
  __syncthreads();
  if (t == 0) outv[j] = (red[0] + red[1] + red[2] + red[3] + bias[j]) * scale;
}

// wmat[h,d] = sum_j qs[h*64+j] * Wk_in[h*64+j, d]   (writes rows 0..15 of 64-row buf)
__global__ __launch_bounds__(256) void k_w(const float* __restrict__ qs,
                                           const float* __restrict__ Wk_in,
                                           float* __restrict__ wmat) {
  int tid = blockIdx.x * 256 + threadIdx.x;
  int h = tid >> 10, d = tid & (kD - 1);
  float acc = 0.f;
  #pragma unroll 8
  for (int j = 0; j < kHD; j++)
    acc = fmaf(qs[h * kHD + j], Wk_in[(size_t)(h * kHD + j) * kD + d], acc);
  wmat[(size_t)h * kD + d] = acc;
}

// cvec[h] = dot(wmat[h,:], bk_lin) + dot(qs[hslice], bk_in[hslice])
__global__ __launch_bounds__(256) void k_c(const float* __restrict__ wmat,
                                           const float* __restrict__ bk_lin,
                                           const float* __restrict__ qs,
                                           const float* __restrict__ bk_in,
                                           float* __restrict__ cvec) {
  int t = threadIdx.x;
  int h = t >> 4, l = t & 15;
  float acc = 0.f;
  for (int d = l; d < kD; d += 16) acc += wmat[h * kD + d] * bk_lin[d];
  for (int j = l; j < kHD; j += 16) acc += qs[h * kHD + j] * bk_in[h * kHD + j];
  #pragma unroll
  for (int o = 8; o >= 1; o >>= 1) acc += __shfl_xor(acc, o, 16);
  if (l == 0) cvec[h] = acc;
}

// out_bf[c][k] = bf16(in[k][c])   (transpose + convert, 1024x1024)
__global__ void k_transpose_cvt(const float* __restrict__ in,
                                __hip_bfloat16* __restrict__ out) {
  __shared__ float tile[32][33];
  int x = blockIdx.x * 32 + threadIdx.x;
  int y0 = blockIdx.y * 32;
  for (int i = threadIdx.y; i < 32; i += 8)
    tile[i][threadIdx.x] = in[(size_t)(y0 + i) * kD + x];
  __syncthreads();
  int xo = blockIdx.y * 32 + threadIdx.x;
  int yo0 = blockIdx.x * 32;
  for (int i = threadIdx.y; i < 32; i += 8)
    out[(size_t)(yo0 + i) * kD + xo] = __float2bfloat16(tile[threadIdx.x][i]);
}

// ---------------- fused attention: scores(MFMA) -> softmax -> eagg(MFMA) ----------------

__global__ __launch_bounds__(256) void k_attn_eagg(const float* __restrict__ ent,
                                                   const unsigned char* __restrict__ pmask,
                                                   const __hip_bfloat16* __restrict__ Ubf,
                                                   const float* __restrict__ cvec,
                                                   __hip_bfloat16* __restrict__ eagg) {
  __shared__ __hip_bfloat16 ent_s[kE][kD + 8];      // pitch 1032 (16B-aligned rows)
  __shared__ float sred[4][kE][kH + 1];             // per-wave partial S^T[e][h]
  __shared__ __hip_bfloat16 attn_b[kH][32];         // attn[h][e], cols 16..31 zero
  int sb = blockIdx.x;
  int s = sb >> 5, b = sb & 31;
  int t = threadIdx.x, l = t & 63, w = t >> 6;
  int quad = l >> 4, lane16 = l & 15;

  // ---- stage E x D entity tile -> LDS bf16 (coalesced 32B/lane loads) ----
  const float* src = ent + (size_t)(s * kE) * kB * kD + (size_t)b * kD;
  #pragma unroll
  for (int it = 0; it < 8; it++) {
    int i = t + it * 256;
    int e = i >> 7, f = (i & 127) * 8;
    const float4* pp = (const float4*)(src + (size_t)e * kB * kD + f);
    float4 v0 = pp[0], v1 = pp[1];
    bf8v pk;
    pk.v[0] = __float2bfloat16(v0.x); pk.v[1] = __float2bfloat16(v0.y);
    pk.v[2] = __float2bfloat16(v0.z); pk.v[3] = __float2bfloat16(v0.w);
    pk.v[4] = __float2bfloat16(v1.x); pk.v[5] = __float2bfloat16(v1.y);
    pk.v[6] = __float2bfloat16(v1.z); pk.v[7] = __float2bfloat16(v1.w);
    *(bf8v*)&ent_s[e][f] = pk;
  }
  __syncthreads();

  // ---- scores: S^T[e,h] = sum_d ent[e,d]*U[h,d]; K-split 256 per wave ----
  fvec4 sacc = {};
  #pragma unroll
  for (int ks = 0; ks < 8; ks++) {
    int k0 = w * 256 + ks * 32 + quad * 8;
    bfvec8 a = *(const bfvec8*)&ent_s[lane16][k0];                 // A[m=e][k=d]
    bfvec8 bb = *(const bfvec8*)&Ubf[(size_t)lane16 * kD + k0];    // B[k=d][n=h]
    sacc = __builtin_amdgcn_mfma_f32_16x16x32_bf16(a, bb, sacc, 0, 0, 0);
  }
  #pragma unroll
  for (int i = 0; i < 4; i++) sred[w][quad * 4 + i][lane16] = sacc[i];
  __syncthreads();

  // ---- softmax over e (thread t: h = t>>4, e = t&15) ----
  {
    int h = t >> 4, e = t & 15;
    float sc = sred[0][e][h] + sred[1][e][h] + sred[2][e][h] + sred[3][e][h] + cvec[h];
    if (pmask[(size_t)(s * kE + e) * kB + b]) sc = -INFINITY;
    float m = sc;
    #pragma unroll
    for (int o = 8; o >= 1; o >>= 1) m = fmaxf(m, __shfl_xor(m, o, 16));
    float ex = __expf(sc - m);
    float sum = ex;
    #pragma unroll
    for (int o = 8; o >= 1; o >>= 1) sum += __shfl_xor(sum, o, 16);
    attn_b[h][e] = __float2bfloat16(ex / sum);
    attn_b[h][e + 16] = __float2bfloat16(0.f);
  }
  __syncthreads();

  // ---- eagg: D[m=d16][n=h] = sum_e ent^T[d,e]*attn[h,e]; 16 d-tiles per wave ----
  bfvec8 bfrag = *(const bfvec8*)&attn_b[lane16][quad * 8];   // B[k=e][n=h], reused
  __hip_bfloat16* dst = eagg + (size_t)sb * (kH * kD);
  for (int tt = 0; tt < 16; tt++) {
    int dme = (w * 16 + tt) * 16 + lane16;    // m = d this lane feeds
    bfvec8 afrag = {};
    if (quad < 2) {
      #pragma unroll
      for (int j = 0; j < 8; j++)
        afrag[j] = *(const short*)&ent_s[quad * 8 + j][dme];  // A[m=d][k=e]
    }
    fvec4 acc = {};
    acc = __builtin_amdgcn_mfma_f32_16x16x32_bf16(afrag, bfrag, acc, 0, 0, 0);
    int d0 = (w * 16 + tt) * 16 + quad * 4;   // output rows quad*4+i, col h=lane16
    bf4 o;
    o.v[0] = __float2bfloat16(acc[0]); o.v[1] = __float2bfloat16(acc[1]);
    o.v[2] = __float2bfloat16(acc[2]); o.v[3] = __float2bfloat16(acc[3]);
    *(bf4*)&dst[(size_t)lane16 * kD + d0] = o;
  }
}

// ---------------- bf16 MFMA GEMM (NT): C[m,n] = sum_k A[m,k]*B[n,k] (+bias) ----------------
// 64x64 tile, 4 waves. MODE 0: f32 out. MODE 2: bf16 out. Bias added if non-null.

__device__ __forceinline__ void stage_row(const __hip_bfloat16* g, __hip_bfloat16* s) {
  *(bf8v*)s = *(const bf8v*)g;
}
__device__ __forceinline__ void stage_row(const float* g, __hip_bfloat16* s) {
  const float4* p = (const float4*)g;
  float4 v0 = p[0], v1 = p[1];
  bf8v pk;
  pk.v[0] = __float2bfloat16(v0.x); pk.v[1] = __float2bfloat16(v0.y);
  pk.v[2] = __float2bfloat16(v0.z); pk.v[3] = __float2bfloat16(v0.w);
  pk.v[4] = __float2bfloat16(v1.x); pk.v[5] = __float2bfloat16(v1.y);
  pk.v[6] = __float2bfloat16(v1.z); pk.v[7] = __float2bfloat16(v1.w);
  *(bf8v*)s = pk;
}

template <int MODE, typename TA, typename TB, typename TC>
__global__ __launch_bounds__(256) void k_gemm_mfma(
    const TA* __restrict__ Abase, int lda, long aBatch,
    const TB* __restrict__ Bbase, int ldb, long bBatch,
    TC* __restrict__ Cbase, int ldc, long cBatch,
    const float* __restrict__ bias, long biasBatch, int Ksz) {
  const TA* Ag = Abase + (size_t)blockIdx.z * aBatch;
  const TB* Bg = Bbase + (size_t)blockIdx.z * bBatch;
  TC* Cg = Cbase + (size_t)blockIdx.z * cBatch;
  const float* biasp = bias ? bias + (size_t)blockIdx.z * biasBatch : nullptr;
  const int m0 = blockIdx.x * 64, n0 = blockIdx.y * 64;
  __shared__ __hip_bfloat16 As[64][72];
  __shared__ __hip_bfloat16 Bs[64][72];
  const int t = threadIdx.x;
  const int l = t & 63, w = t >> 6;
  const int quad = l >> 4, col = l & 15;
  fvec4 acc[4] = {};
  for (int k0 = 0; k0 < Ksz; k0 += 64) {
    #pragma unroll
    for (int c = t; c < 512; c += 256) {
      int row = c >> 3, kq = (c & 7) * 8;
      stage_row(Ag + (size_t)(m0 + row) * lda + k0 + kq, &As[row][kq]);
      stage_row(Bg + (size_t)(n0 + row) * ldb + k0 + kq, &Bs[row][kq]);
    }
    __syncthreads();
    #pragma unroll
    for (int ks = 0; ks < 64; ks += 32) {
      bfvec8 a = *(const bfvec8*)&As[w * 16 + col][ks + quad * 8];
      #pragma unroll
      for (int nt = 0; nt < 4; nt++) {
        bfvec8 b = *(const bfvec8*)&Bs[nt * 16 + col][ks + quad * 8];
        acc[nt] = __builtin_amdgcn_mfma_f32_16x16x32_bf16(a, b, acc[nt], 0, 0, 0);
      }
    }
    __syncthreads();
  }
  #pragma unroll
  for (int nt = 0; nt < 4; nt++) {
    int n = n0 + nt * 16 + col;
    float bv = biasp ? biasp[n] : 0.f;
    #pragma unroll
    for (int i = 0; i < 4; i++) {
      int r = m0 + w * 16 + quad * 4 + i;
      float v = acc[nt][i] + bv;
      if constexpr (MODE == 0) {
        ((float*)Cg)[(size_t)r * ldc + n] = v;
      } else {
        ((__hip_bfloat16*)Cg)[(size_t)r * ldc + n] = __float2bfloat16(v);
      }
    }
  }
}

extern "C" void kernel_launch(void* const* d_in, const int* in_sizes, int n_in,
                              void* d_out, int out_size, void* d_ws, size_t ws_size,
                              hipStream_t stream) {
  const float* ent            = (const float*)d_in[0];
  const unsigned char* pmask  = (const unsigned char*)d_in[1];
  const float* query          = (const float*)d_in[3];
  const float* Wk_lin         = (const float*)d_in[4];
  const float* bk_lin         = (const float*)d_in[5];
  const float* Wv_lin         = (const float*)d_in[6];
  const float* bv_lin         = (const float*)d_in[7];
  const float* Wq_in          = (const float*)d_in[8];
  const float* bq_in          = (const float*)d_in[9];
  const float* Wk_in          = (const float*)d_in[10];
  const float* bk_in          = (const float*)d_in[11];
  const float* Wv_in          = (const float*)d_in[12];
  const float* bv_in          = (const float*)d_in[13];
  const float* Wo             = (const float*)d_in[14];
  const float* bo             = (const float*)d_in[15];
  float* out = (float*)d_out;

  float* p = (float*)d_ws;
  float* qs   = p; p += 1024;            // scaled projected query
  float* wmat = p; p += 64 * kD;         // w[h,d] rows 0..15 valid (64-row pad for GEMM)
  float* cvec = p; p += 256;             // c[h]
  float* cb   = p; p += kD;              // Wv_in@bv_lin + bv_in
  __hip_bfloat16* bp = (__hip_bfloat16*)p;
  __hip_bfloat16* TT   = bp; bp += (size_t)kD * kD;    // shared transpose buffer (bf16)
  __hip_bfloat16* Ubf  = bp; bp += (size_t)64 * kD;    // U[h][d] bf16 (rows 0..15 valid)
  __hip_bfloat16* Mmat = bp; bp += (size_t)kD * kD;    // Wv_in @ Wv_lin bf16
  __hip_bfloat16* ctx2 = bp; bp += (size_t)kSB * kD;   // ctx bf16 [SB, D]
  __hip_bfloat16* eagg = bp;                           // [SB, H, D] bf16

  // ---- folded-weight precomputes ----
  k_rowdot<<<kD, 256, 0, stream>>>(Wq_in, query, bq_in, 0.125f, qs);
  k_w<<<64, 256, 0, stream>>>(qs, Wk_in, wmat);
  k_c<<<1, 256, 0, stream>>>(wmat, bk_lin, qs, bk_in, cvec);
  k_rowdot<<<kD, 256, 0, stream>>>(Wv_in, bv_lin, bv_in, 1.0f, cb);
  // U = wmat @ Wk_lin   (transpose Wk_lin -> bf16, then MFMA GEMM, bf16 out)
  k_transpose_cvt<<<dim3(32, 32), dim3(32, 8), 0, stream>>>(Wk_lin, TT);
  k_gemm_mfma<2><<<dim3(1, 16, 1), 256, 0, stream>>>(
      wmat, kD, 0L, TT, kD, 0L, Ubf, kD, 0L, (const float*)nullptr, 0L, kD);
  // M = Wv_in @ Wv_lin  (reuse TT; stream order guarantees U-GEMM finished)
  k_transpose_cvt<<<dim3(32, 32), dim3(32, 8), 0, stream>>>(Wv_lin, TT);
  k_gemm_mfma<2><<<dim3(16, 16, 1), 256, 0, stream>>>(
      Wv_in, kD, 0L, TT, kD, 0L, Mmat, kD, 0L, (const float*)nullptr, 0L, kD);

  // ---- main pipeline ----
  k_attn_eagg<<<kSB, 256, 0, stream>>>(ent, pmask, Ubf, cvec, eagg);
  // ctx[sb, h*64+j] = M_h @ eagg[sb,h,:] + cb   (batched over h = z), bf16 out
  k_gemm_mfma<2><<<dim3(kSB / 64, 1, kH), 256, 0, stream>>>(
      eagg, kH * kD, (long)kD, Mmat, kD, (long)(kHD * kD),
      ctx2, kD, (long)kHD, cb, (long)kHD, kD);
  // out = ctx @ Wo^T + bo  (Wo f32 converted in staging)
  k_gemm_mfma<0><<<dim3(kSB / 64, kD / 64, 1), 256, 0, stream>>>(
      ctx2, kD, 0L, Wo, kD, 0L, out, kD, 0L, bo, 0L, kD);
}